// Round 8
// baseline (437.234 us; speedup 1.0000x reference)
//
#include <hip/hip_runtime.h>

// RadarPillarFE: scatter-mean of (B,N,18) fp32 points into (B,18,256,256) fp32 BEV grid.
// R12: dense compaction with SHARDED allocator + R9's 4-lane-per-voxel reduce.
//   pass1 (bin):  strided float4 xyz read (full 288MB fetch, unavoidable); survivors
//                 (15.5%) get a compact slot via PER-WAVE ballot + 1 atomicAdd on one of
//                 64 sharded counters (64B apart) -> no single-address RMW hotspot (R8's
//                 bug, ~130us). Record stored as 80B-aligned 5xfloat4 in its partition,
//                 partitions fill densely -> touched lines ~50MB. Voxel list stores cid.
//   pass2 (reduce): R9 champion mapping (4 threads/voxel, slot-interleaved, shfl_xor
//                 combine) but gathers 5xfloat4 from the DENSE compact buffer
//                 (cache-resident; R8 measured this reduce at ~30us vs ~60 from pts).

#define B_     8
#define NPTS   500000
#define F_     18
#define NX_    256
#define NY_    256
#define NVOX   (NX_ * NY_)         // 65536
#define BN     (B_ * NPTS)         // 4,000,000
#define NVOXT  (B_ * NVOX)         // 524,288 voxels total
#define CAP    32                  // list slots per voxel (max expected occupancy ~25)
#define RSTRIDE 20                 // compact record stride in floats (80 B)
#define NPART  64                  // allocator shards
#define CAPREC 65536               // records per partition (worst case 62528, proven)

// under-aligned vector types: legal on 8B-aligned addresses, still emit dwordx4/dwordx2
typedef float float4u __attribute__((ext_vector_type(4), aligned(4)));
typedef float float2u __attribute__((ext_vector_type(2), aligned(4)));

__global__ __launch_bounds__(256) void bin_kernel(const float* __restrict__ pts,
                                                  unsigned* __restrict__ cnt,
                                                  unsigned* __restrict__ list,
                                                  float* __restrict__ compact,
                                                  unsigned* __restrict__ gcount) {
    const int tid = threadIdx.x;
    const int p = blockIdx.x * 256 + tid;             // grid exact: BN/256 = 15625
    const float* rec = pts + (size_t)p * F_;          // 72B record, 8B-aligned
    float4u a = *(const float4u*)rec;                 // x,y,z,f3 : one address
    float x = a.x, y = a.y, z = a.z;
    bool ok = (x >= -51.2f) & (x <= 51.2f) &
              (y >= -51.2f) & (y <= 51.2f) &
              (z >= -5.0f)  & (z <= 3.0f);

    unsigned long long m = __ballot(ok);              // wave-level compaction (no LDS/barrier)
    if (!ok) return;                                  // ~84.5% exit, after ballot

    const int lane = tid & 63;
    const int w    = tid >> 6;
    const int leader = (int)__ffsll((unsigned long long)m) - 1;   // lowest active lane
    unsigned nact = (unsigned)__popcll(m);
    unsigned rank = (unsigned)__popcll(m & ((1ull << lane) - 1ull));
    const int part = (blockIdx.x * 4 + w) & (NPART - 1);

    unsigned base;
    if (lane == leader)
        base = atomicAdd(gcount + part * 16, nact);   // sharded: ~980 RMWs per address
    base = __shfl(base, leader);                      // broadcast from active leader

    unsigned cid = (unsigned)part * CAPREC + base + rank;   // dense within partition

    // materialize the 80B record: tail read hits L1/L2 (lines just fetched), store
    // is ~800B contiguous per wave (survivors pack rank-adjacent slots).
    float4u t1 = ((const float4u*)rec)[1];
    float4u t2 = ((const float4u*)rec)[2];
    float4u t3 = ((const float4u*)rec)[3];
    float2u t4 = *(const float2u*)(rec + 16);
    float4* dst = (float4*)(compact + (size_t)cid * RSTRIDE);
    dst[0] = make_float4(a.x,  a.y,  a.z,  a.w);
    dst[1] = make_float4(t1.x, t1.y, t1.z, t1.w);
    dst[2] = make_float4(t2.x, t2.y, t2.z, t2.w);
    dst[3] = make_float4(t3.x, t3.y, t3.z, t3.w);
    dst[4] = make_float4(t4.x, t4.y, 0.0f, 0.0f);     // full-line 80B write, no partials

    int ix = min(max((int)((x + 51.2f) * 2.5f), 0), NX_ - 1);
    int iy = min(max((int)((y + 51.2f) * 2.5f), 0), NY_ - 1);
    int b  = p / NPTS;
    int vox = b * NVOX + iy * NX_ + ix;

    unsigned slot = atomicAdd(cnt + vox, 1u);         // low-contention per-voxel atomic
    if (slot < CAP) list[(size_t)slot * NVOXT + vox] = cid;  // transposed: coalesced reads
}

__global__ __launch_bounds__(256) void reduce_kernel(const unsigned* __restrict__ cnt,
                                                     const unsigned* __restrict__ list,
                                                     const float* __restrict__ compact,
                                                     float* __restrict__ out) {
    int t = blockIdx.x * 256 + threadIdx.x;           // 4 threads per voxel
    int v = t >> 2;                                   // voxel id; grid: NVOXT*4/256 = 8192
    int k = t & 3;                                    // slot phase
    int b   = v >> 16;                                // NVOX == 65536
    int pos = v & (NVOX - 1);

    unsigned c = min(cnt[v], (unsigned)CAP);

    float s[F_];
#pragma unroll
    for (int f = 0; f < F_; ++f) s[f] = 0.0f;

    for (unsigned i = k; i < c; i += 4) {             // <=7 iters; 4x MLP on gathers
        unsigned cid = list[(size_t)i * NVOXT + v];   // 16-lane-coalesced per phase
        const float4* rp = (const float4*)(compact + (size_t)cid * RSTRIDE);
        float4 w0 = rp[0], w1 = rp[1], w2 = rp[2], w3 = rp[3], w4 = rp[4];
        s[0]  += w0.x; s[1]  += w0.y; s[2]  += w0.z; s[3]  += w0.w;
        s[4]  += w1.x; s[5]  += w1.y; s[6]  += w1.z; s[7]  += w1.w;
        s[8]  += w2.x; s[9]  += w2.y; s[10] += w2.z; s[11] += w2.w;
        s[12] += w3.x; s[13] += w3.y; s[14] += w3.z; s[15] += w3.w;
        s[16] += w4.x; s[17] += w4.y;
    }

    // combine the 4 partial sums within each 4-lane group (wave=64, xor 1 then 2)
#pragma unroll
    for (int f = 0; f < F_; ++f) {
        s[f] += __shfl_xor(s[f], 1);
        s[f] += __shfl_xor(s[f], 2);
    }

    if (k == 0) {
        float rcp = (c > 0) ? (1.0f / (float)c) : 0.0f;   // empty voxel -> exact 0
        float* ob = out + (((size_t)b * F_) << 16) + pos; // (b, f, y, x) per-f stores
#pragma unroll
        for (int f = 0; f < F_; ++f) ob[(size_t)f << 16] = s[f] * rcp;
    }
}

extern "C" void kernel_launch(void* const* d_in, const int* in_sizes, int n_in,
                              void* d_out, int out_size, void* d_ws, size_t ws_size,
                              hipStream_t stream) {
    const float* pts = (const float*)d_in[0];
    float* out = (float*)d_out;
    // workspace layout (~405 MB of ~1.1 GB):
    float* compact  = (float*)d_ws;                            // 64*65536*20 f32 = 335.5 MB
    unsigned* list  = (unsigned*)(compact + (size_t)NPART * CAPREC * RSTRIDE); // 67 MB
    unsigned* cnt   = list + (size_t)CAP * NVOXT;              // NVOXT u32 = 2 MB
    unsigned* gcount = cnt + NVOXT;                            // 64 shards * 64B = 4 KB

    // zero cnt + gcount in one call
    hipMemsetAsync(cnt, 0, (size_t)(NVOXT + NPART * 16) * sizeof(unsigned), stream);

    bin_kernel<<<BN / 256, 256, 0, stream>>>(pts, cnt, list, compact, gcount);
    reduce_kernel<<<(NVOXT * 4) / 256, 256, 0, stream>>>(cnt, list, compact, out);
}

// Round 9
// 434.137 us; speedup vs baseline: 1.0071x; 1.0071x over previous
//
#include <hip/hip_runtime.h>

// RadarPillarFE: scatter-mean of (B,N,18) fp32 points into (B,18,256,256) fp32 BEV grid.
// R13 = R9 champion with a shorter reduce dependency chain.
//   pass1 (bin):    UNCHANGED R9: mask -> voxel -> slot=atomicAdd(cnt[vox]) -> store idx.
//   pass2 (reduce): EIGHT threads per voxel, pure slot axis (R10's record-splitting
//                   mistake avoided): <=4 iterations instead of <=7, plus an explicit
//                   list-index prefetch so each iteration's chain is ~one record-gather
//                   latency. Combine partials via __shfl_xor 1,2,4; lane 0 writes.

#define B_     8
#define NPTS   500000
#define F_     18
#define NX_    256
#define NY_    256
#define NVOX   (NX_ * NY_)         // 65536
#define BN     (B_ * NPTS)         // 4,000,000
#define NVOXT  (B_ * NVOX)         // 524,288 voxels total
#define CAP    32                  // slots per voxel (max expected occupancy ~25)

__global__ __launch_bounds__(256) void bin_kernel(const float* __restrict__ pts,
                                                  unsigned* __restrict__ cnt,
                                                  unsigned* __restrict__ list) {
    int p = blockIdx.x * 256 + threadIdx.x;          // grid exact: BN/256 = 15625
    const float2* rp = (const float2*)(pts + (size_t)p * F_);   // 72B records, 8B-aligned
    float2 a0 = rp[0];
    float2 a1 = rp[1];
    float x = a0.x, y = a0.y, z = a1.x;
    bool ok = (x >= -51.2f) & (x <= 51.2f) &
              (y >= -51.2f) & (y <= 51.2f) &
              (z >= -5.0f)  & (z <= 3.0f);
    if (!ok) return;                                  // ~84.5% exit

    int ix = min(max((int)((x + 51.2f) * 2.5f), 0), NX_ - 1);
    int iy = min(max((int)((y + 51.2f) * 2.5f), 0), NY_ - 1);
    int b  = p / NPTS;
    int vox = b * NVOX + iy * NX_ + ix;

    unsigned slot = atomicAdd(cnt + vox, 1u);         // the ONE atomic, low contention
    if (slot < CAP) list[(size_t)slot * NVOXT + vox] = (unsigned)p;  // transposed: coalesced reads
}

__global__ __launch_bounds__(256) void reduce_kernel(const float* __restrict__ pts,
                                                     const unsigned* __restrict__ cnt,
                                                     const unsigned* __restrict__ list,
                                                     float* __restrict__ out) {
    int t = blockIdx.x * 256 + threadIdx.x;           // 8 threads per voxel
    int v = t >> 3;                                   // voxel id; grid: NVOXT*8/256 = 16384
    int k = t & 7;                                    // slot phase 0..7
    int b   = v >> 16;                                // NVOX == 65536
    int pos = v & (NVOX - 1);

    unsigned c = min(cnt[v], (unsigned)CAP);

    float s[F_];
#pragma unroll
    for (int f = 0; f < F_; ++f) s[f] = 0.0f;

    // rotate prefetch: the next list index loads while the current record gathers,
    // so each of the <=4 iterations costs ~one gather latency, not list+gather.
    unsigned pnext = 0;
    if (k < c) pnext = list[(size_t)k * NVOXT + v];
    for (unsigned i = k; i < c; i += 8) {
        unsigned p = pnext;
        if (i + 8 < c) pnext = list[(size_t)(i + 8) * NVOXT + v];
        const float2* rp = (const float2*)(pts + (size_t)p * F_);
#pragma unroll
        for (int j = 0; j < 9; ++j) {                 // 72B random gather, 8B-aligned loads
            float2 q = rp[j];
            s[2 * j]     += q.x;
            s[2 * j + 1] += q.y;
        }
    }

    // combine the 8 partial sums within each 8-lane group (wave=64: xor 1, 2, 4)
#pragma unroll
    for (int f = 0; f < F_; ++f) {
        s[f] += __shfl_xor(s[f], 1);
        s[f] += __shfl_xor(s[f], 2);
        s[f] += __shfl_xor(s[f], 4);
    }

    if (k == 0) {
        float rcp = (c > 0) ? (1.0f / (float)c) : 0.0f;   // empty voxel -> exact 0
        float* ob = out + (((size_t)b * F_) << 16) + pos; // (b, f, y, x) per-f stores
#pragma unroll
        for (int f = 0; f < F_; ++f) ob[(size_t)f << 16] = s[f] * rcp;
    }
}

extern "C" void kernel_launch(void* const* d_in, const int* in_sizes, int n_in,
                              void* d_out, int out_size, void* d_ws, size_t ws_size,
                              hipStream_t stream) {
    const float* pts = (const float*)d_in[0];
    float* out = (float*)d_out;
    unsigned* cnt  = (unsigned*)d_ws;                 // 524,288 u32 = 2 MB
    unsigned* list = cnt + NVOXT;                     // CAP * 524,288 u32 = 67 MB

    hipMemsetAsync(cnt, 0, (size_t)NVOXT * sizeof(unsigned), stream);

    bin_kernel<<<BN / 256, 256, 0, stream>>>(pts, cnt, list);
    reduce_kernel<<<(NVOXT * 8) / 256, 256, 0, stream>>>(pts, cnt, list, out);
}

// Round 10
// 423.628 us; speedup vs baseline: 1.0321x; 1.0248x over previous
//
#include <hip/hip_runtime.h>

// RadarPillarFE: scatter-mean of (B,N,18) fp32 points into (B,18,256,256) fp32 BEV grid.
// R14 = byte-exact revert to R9 (champion, 414.8 us).
//   pass1 (bin):    mask -> voxel id -> slot = atomicAdd(per-VOXEL counter) -> store point idx
//                   (1 device atomic per in-range point, ~5 hits max per counter)
//   pass2 (reduce): FOUR threads per voxel walk interleaved slots (<=7 iters instead of <=25),
//                   4x the memory-level parallelism on the random 72B gathers, then a 2-step
//                   __shfl_xor tree combines the 18 partial sums inside each 4-lane group.
// Measured design space (R5-R13): bin is pattern-bound at ~70us (coalesced staging = null);
// reduce is random-line-throughput-bound at ~60us (1/4/8 lanes = 90/60/80; wide loads null;
// dense-gather materialization: bin cost +54..140 > reduce saving -30, 3 variants; direct
// atomics +500). 4 lanes/voxel is the measured optimum on every axis.

#define B_     8
#define NPTS   500000
#define F_     18
#define NX_    256
#define NY_    256
#define NVOX   (NX_ * NY_)         // 65536
#define BN     (B_ * NPTS)         // 4,000,000
#define NVOXT  (B_ * NVOX)         // 524,288 voxels total
#define CAP    32                  // slots per voxel (max expected occupancy ~25)

__global__ __launch_bounds__(256) void bin_kernel(const float* __restrict__ pts,
                                                  unsigned* __restrict__ cnt,
                                                  unsigned* __restrict__ list) {
    int p = blockIdx.x * 256 + threadIdx.x;          // grid exact: BN/256 = 15625
    const float2* rp = (const float2*)(pts + (size_t)p * F_);   // 72B records, 8B-aligned
    float2 a0 = rp[0];
    float2 a1 = rp[1];
    float x = a0.x, y = a0.y, z = a1.x;
    bool ok = (x >= -51.2f) & (x <= 51.2f) &
              (y >= -51.2f) & (y <= 51.2f) &
              (z >= -5.0f)  & (z <= 3.0f);
    if (!ok) return;                                  // ~84.5% exit

    int ix = min(max((int)((x + 51.2f) * 2.5f), 0), NX_ - 1);
    int iy = min(max((int)((y + 51.2f) * 2.5f), 0), NY_ - 1);
    int b  = p / NPTS;
    int vox = b * NVOX + iy * NX_ + ix;

    unsigned slot = atomicAdd(cnt + vox, 1u);         // the ONE atomic, low contention
    if (slot < CAP) list[(size_t)slot * NVOXT + vox] = (unsigned)p;  // transposed: coalesced reads
}

__global__ __launch_bounds__(256) void reduce_kernel(const float* __restrict__ pts,
                                                     const unsigned* __restrict__ cnt,
                                                     const unsigned* __restrict__ list,
                                                     float* __restrict__ out) {
    int t = blockIdx.x * 256 + threadIdx.x;           // 4 threads per voxel
    int v = t >> 2;                                   // voxel id; grid: NVOXT*4/256 = 8192
    int k = t & 3;                                    // slot phase
    int b   = v >> 16;                                // NVOX == 65536
    int pos = v & (NVOX - 1);

    unsigned c = min(cnt[v], (unsigned)CAP);

    float s[F_];
#pragma unroll
    for (int f = 0; f < F_; ++f) s[f] = 0.0f;

    for (unsigned i = k; i < c; i += 4) {             // <=7 iters; 4x MLP on gathers
        unsigned p = list[(size_t)i * NVOXT + v];     // 16-lane-coalesced segments
        const float2* rp = (const float2*)(pts + (size_t)p * F_);
#pragma unroll
        for (int j = 0; j < 9; ++j) {                 // 72B random gather, 8B-aligned loads
            float2 q = rp[j];
            s[2 * j]     += q.x;
            s[2 * j + 1] += q.y;
        }
    }

    // combine the 4 partial sums within each 4-lane group (wave=64, xor 1 then 2)
#pragma unroll
    for (int f = 0; f < F_; ++f) {
        s[f] += __shfl_xor(s[f], 1);
        s[f] += __shfl_xor(s[f], 2);
    }

    if (k == 0) {
        float rcp = (c > 0) ? (1.0f / (float)c) : 0.0f;   // empty voxel -> exact 0
        float* ob = out + (((size_t)b * F_) << 16) + pos; // (b, f, y, x) per-f stores
#pragma unroll
        for (int f = 0; f < F_; ++f) ob[(size_t)f << 16] = s[f] * rcp;
    }
}

extern "C" void kernel_launch(void* const* d_in, const int* in_sizes, int n_in,
                              void* d_out, int out_size, void* d_ws, size_t ws_size,
                              hipStream_t stream) {
    const float* pts = (const float*)d_in[0];
    float* out = (float*)d_out;
    unsigned* cnt  = (unsigned*)d_ws;                 // 524,288 u32 = 2 MB
    unsigned* list = cnt + NVOXT;                     // CAP * 524,288 u32 = 67 MB

    hipMemsetAsync(cnt, 0, (size_t)NVOXT * sizeof(unsigned), stream);

    bin_kernel<<<BN / 256, 256, 0, stream>>>(pts, cnt, list);
    reduce_kernel<<<(NVOXT * 4) / 256, 256, 0, stream>>>(pts, cnt, list, out);
}